// Round 7
// baseline (4918.044 us; speedup 1.0000x reference)
//
#include <hip/hip_runtime.h>
#include <cstdint>
#include <cstddef>

#define BATCH 16384

typedef float f32x4 __attribute__((ext_vector_type(4)));
typedef _Float16 f16x8 __attribute__((ext_vector_type(8)));

__device__ __forceinline__ unsigned short f2h_bits(float f) {
  _Float16 h = (_Float16)f;
  return __builtin_bit_cast(unsigned short, h);
}

__device__ __forceinline__ void async_cp16(const void* g, void* l) {
  __builtin_amdgcn_global_load_lds(
      (const __attribute__((address_space(1))) unsigned int*)g,
      (__attribute__((address_space(3))) unsigned int*)l, 16, 0, 0);
}

// Barrier WITHOUT the full vmcnt(0) drain __syncthreads would force.
#define PIPE_BAR_4() asm volatile("s_waitcnt vmcnt(4)\n\ts_barrier" ::: "memory")
#define PIPE_BAR_0() asm volatile("s_waitcnt vmcnt(0)\n\ts_barrier" ::: "memory")

// ---------------------------------------------------------------------------
// Hidden-layer GEMM, 3-stage software-pipelined LDS staging, 3 blocks/CU.
// C = relu(A[M,K] * Bw[N,K]^T + (bias + t*W[:,K])).
// Block 128x128, 4 waves 2x2, wave tile 64x64 (RT=CT=4), BK=32.
// Per stage each thread issues exactly 4 global_load_lds (A:2, B:2).
// Iter k: s_waitcnt vmcnt(4) [stage k done, stage k+1 STAYS IN FLIGHT],
// s_barrier, issue stage k+2 into buffer (k+2)%3, compute stage k.
// 3 co-resident blocks' barriers interleave -> 3 waves/SIMD cover each
// other's drain windows (R4-R6's 2-block residency could not).
// XOR swizzle cp = c ^ ((row>>1)&3): frag ds_read_b128 2-way max (free).
// ---------------------------------------------------------------------------
template <int BM, int BN, int RT, int CT, int K, int N, bool RELU>
__launch_bounds__(256, 3)
__global__ void gemm_h(const unsigned short* __restrict__ A,
                       const unsigned short* __restrict__ Bw,
                       const float* __restrict__ Wfull,
                       const float* __restrict__ bias,
                       float tval,
                       unsigned short* __restrict__ Ch) {
  constexpr int BK = 32;
  constexpr int NI = K / BK;
  static_assert(NI >= 2, "pipeline needs >=2 stages");
  static_assert((BM * 4 + BN * 4) / 256 == 4, "vmcnt(4) assumes 4 loads/stage");
  __shared__ __align__(16) unsigned short smA[3][BM * BK];
  __shared__ __align__(16) unsigned short smB[3][BN * BK];
  __shared__ float biasLds[BN];

  const int tid = threadIdx.x;
  const int wave = tid >> 6;
  const int lane = tid & 63;
  const int quad = lane >> 4;
  const int r16 = lane & 15;

  const int rowA0 = blockIdx.x * BM;
  const int rowB0 = blockIdx.y * BN;
  const int waveM = wave >> 1;  // 2 wave-rows
  const int waveN = wave & 1;   // 2 wave-cols

  // effective bias = b[col] + t * W[col][K] (time-column fold); its vmcnt
  // drain happens once, before the pipeline starts.
  if (tid < BN) {
    const int col = rowB0 + tid;
    biasLds[tid] = bias[col] + tval * Wfull[(size_t)col * (K + 1) + K];
  }

  auto stage = [&](int k0, int buf) {
#pragma unroll
    for (int i = 0; i < BM * 4 / 256; ++i) {
      const int s = i * 256 + tid;                // LDS 16B-chunk position
      const int row = s >> 2;
      const int c = (s & 3) ^ ((row >> 1) & 3);   // global chunk (swizzled)
      const unsigned short* g = A + (size_t)(rowA0 + row) * K + (k0 + c * 8);
      char* l = ((char*)smA[buf]) + (size_t)(i * 256 + (wave << 6)) * 16;
      async_cp16(g, l);
    }
#pragma unroll
    for (int i = 0; i < BN * 4 / 256; ++i) {
      const int s = i * 256 + tid;
      const int row = s >> 2;
      const int c = (s & 3) ^ ((row >> 1) & 3);
      const unsigned short* g = Bw + (size_t)(rowB0 + row) * K + (k0 + c * 8);
      char* l = ((char*)smB[buf]) + (size_t)(i * 256 + (wave << 6)) * 16;
      async_cp16(g, l);
    }
  };

  f32x4 acc[RT][CT];
  const f32x4 zero = {0.f, 0.f, 0.f, 0.f};
#pragma unroll
  for (int i = 0; i < RT; ++i)
#pragma unroll
    for (int j = 0; j < CT; ++j) acc[i][j] = zero;

  auto compute = [&](int buf) {
    const unsigned short* sA = smA[buf];
    const unsigned short* sB = smB[buf];
    f16x8 af[RT], bfr[CT];
#pragma unroll
    for (int nt = 0; nt < CT; ++nt) {
      const int row = (waveN * CT + nt) * 16 + r16;
      const int cp = quad ^ ((row >> 1) & 3);
      bfr[nt] = *(const f16x8*)(sB + row * BK + cp * 8);
    }
#pragma unroll
    for (int mt = 0; mt < RT; ++mt) {
      const int row = (waveM * RT + mt) * 16 + r16;
      const int cp = quad ^ ((row >> 1) & 3);
      af[mt] = *(const f16x8*)(sA + row * BK + cp * 8);
    }
#pragma unroll
    for (int mt = 0; mt < RT; ++mt)
#pragma unroll
      for (int nt = 0; nt < CT; ++nt)
        acc[mt][nt] =
            __builtin_amdgcn_mfma_f32_16x16x32_f16(af[mt], bfr[nt], acc[mt][nt], 0, 0, 0);
  };

  stage(0, 0);
  stage(BK, 1);

#pragma unroll
  for (int kk = 0; kk < NI - 1; ++kk) {
    PIPE_BAR_4();  // stage kk complete; stage kk+1 still in flight
    if (kk + 2 < NI) stage((kk + 2) * BK, (kk + 2) % 3);
    compute(kk % 3);
  }
  PIPE_BAR_0();  // tail: drain the final stage
  compute((NI - 1) % 3);

  // epilogue: C/D layout col=lane&15, row=(lane>>4)*4+r
#pragma unroll
  for (int mt = 0; mt < RT; ++mt) {
    const int grow0 = rowA0 + (waveM * RT + mt) * 16 + quad * 4;
#pragma unroll
    for (int nt = 0; nt < CT; ++nt) {
      const int lcol = (waveN * CT + nt) * 16 + r16;
      const int gcol = rowB0 + lcol;
      const float bi = biasLds[lcol];
#pragma unroll
      for (int r = 0; r < 4; ++r) {
        float v = acc[mt][nt][r] + bi;
        if (RELU) v = fmaxf(v, 0.0f);
        Ch[(size_t)(grow0 + r) * N + gcol] = f2h_bits(v);
      }
    }
  }
}

// ---------------------------------------------------------------------------
// Last layer fused with RK4 combine (BM=32, BN=64 full width), dbuf BK=32.
// ---------------------------------------------------------------------------
__launch_bounds__(256, 4)
__global__ void gemm_l4(const unsigned short* __restrict__ A,
                        const unsigned short* __restrict__ Bw,
                        const float* __restrict__ Wfull,
                        const float* __restrict__ bias,
                        float tval,
                        float* __restrict__ y, float* __restrict__ ksum,
                        unsigned short* __restrict__ yh,
                        float* __restrict__ outp, int mode, float dt) {
  constexpr int K = 1024, BK = 32, BM = 32, BN = 64, NI = K / BK;
  __shared__ __align__(16) unsigned short smA[2][BM * BK];
  __shared__ __align__(16) unsigned short smB[2][BN * BK];
  __shared__ float biasLds[BN];

  const int tid = threadIdx.x;
  const int wave = tid >> 6;
  const int lane = tid & 63;
  const int quad = lane >> 4;
  const int r16 = lane & 15;

  const int rowA0 = blockIdx.x * BM;
  const int waveM = wave >> 1;
  const int waveN = wave & 1;

  if (tid < BN) {
    biasLds[tid] = bias[tid] + tval * Wfull[(size_t)tid * (K + 1) + K];
  }

  auto stage = [&](int k0, int buf) {
    if (tid < BM * 4) {  // A: 128 chunks
      const int s = tid;
      const int row = s >> 2;
      const int c = (s & 3) ^ ((row >> 1) & 3);
      const unsigned short* g = A + (size_t)(rowA0 + row) * K + (k0 + c * 8);
      char* l = ((char*)smA[buf]) + (size_t)(wave << 6) * 16;
      async_cp16(g, l);
    }
    {  // B: 256 chunks
      const int s = tid;
      const int row = s >> 2;
      const int c = (s & 3) ^ ((row >> 1) & 3);
      const unsigned short* g = Bw + (size_t)row * K + (k0 + c * 8);
      char* l = ((char*)smB[buf]) + (size_t)(wave << 6) * 16;
      async_cp16(g, l);
    }
  };

  f32x4 acc[2];
  const f32x4 zero = {0.f, 0.f, 0.f, 0.f};
  acc[0] = zero; acc[1] = zero;

  stage(0, 0);

#pragma unroll 2
  for (int kk = 0; kk < NI; ++kk) {
    __syncthreads();
    if (kk + 1 < NI) stage((kk + 1) * BK, (kk + 1) & 1);

    const unsigned short* sA = smA[kk & 1];
    const unsigned short* sB = smB[kk & 1];
    f16x8 af, bfr[2];
    {
      const int row = waveM * 16 + r16;
      const int cp = quad ^ ((row >> 1) & 3);
      af = *(const f16x8*)(sA + row * BK + cp * 8);
    }
#pragma unroll
    for (int nt = 0; nt < 2; ++nt) {
      const int row = (waveN * 2 + nt) * 16 + r16;
      const int cp = quad ^ ((row >> 1) & 3);
      bfr[nt] = *(const f16x8*)(sB + row * BK + cp * 8);
    }
#pragma unroll
    for (int nt = 0; nt < 2; ++nt)
      acc[nt] = __builtin_amdgcn_mfma_f32_16x16x32_f16(af, bfr[nt], acc[nt], 0, 0, 0);
  }

  // epilogue + fused RK4 combine
  const int grow0 = rowA0 + waveM * 16 + quad * 4;
#pragma unroll
  for (int nt = 0; nt < 2; ++nt) {
    const int col = waveN * 32 + nt * 16 + r16;
    const float bi = biasLds[col];
#pragma unroll
    for (int r = 0; r < 4; ++r) {
      const float k = acc[nt][r] + bi;
      const int row = grow0 + r;
      const int idx = row * 64 + col;
      if (mode == 0) {
        ksum[idx] = k;
        yh[idx] = f2h_bits(y[idx] + 0.5f * dt * k);
      } else if (mode == 1) {
        ksum[idx] += 2.f * k;
        yh[idx] = f2h_bits(y[idx] + 0.5f * dt * k);
      } else if (mode == 2) {
        ksum[idx] += 2.f * k;
        yh[idx] = f2h_bits(y[idx] + dt * k);
      } else {
        const float yn = y[idx] + (dt / 6.f) * (ksum[idx] + k);
        y[idx] = yn;
        yh[idx] = f2h_bits(yn);
        if (outp && col < 32) outp[row * 32 + col] = yn;
      }
    }
  }
}

// fp32 W (N x (K+1), time col dropped) -> fp16 Wh (N x K), row-major
__global__ void conv_w(const float* __restrict__ W, unsigned short* __restrict__ Wh,
                       int N, int K) {
  const int idx = blockIdx.x * 256 + threadIdx.x;
  if (idx < N * K) {
    const int n = idx / K;
    const int k = idx - n * K;
    Wh[idx] = f2h_bits(W[(size_t)n * (K + 1) + k]);
  }
}

// y0 = concat(x, aug); row-major fp32 + fp16 copy
__global__ void init_y(const float* __restrict__ x, const float* __restrict__ aug,
                       float* __restrict__ y, unsigned short* __restrict__ yh) {
  const int idx = blockIdx.x * 256 + threadIdx.x;  // BATCH*64
  const int i = idx >> 6;
  const int j = idx & 63;
  const float v = (j < 32) ? x[i * 32 + j] : aug[i * 32 + (j - 32)];
  y[idx] = v;
  yh[idx] = f2h_bits(v);
}

extern "C" void kernel_launch(void* const* d_in, const int* in_sizes, int n_in,
                              void* d_out, int out_size, void* d_ws, size_t ws_size,
                              hipStream_t stream) {
  const float* x = (const float*)d_in[0];
  const float* aug = (const float*)d_in[1];
  const float* W[5];
  const float* b[5];
  for (int i = 0; i < 5; ++i) {
    W[i] = (const float*)d_in[2 + 2 * i];
    b[i] = (const float*)d_in[3 + 2 * i];
  }

  char* ws = (char*)d_ws;
  auto alloc = [&](size_t bytes) -> char* {
    char* p = ws;
    ws += (bytes + 255) & ~(size_t)255;
    return p;
  };
  float* y = (float*)alloc((size_t)BATCH * 64 * 4);
  unsigned short* yh = (unsigned short*)alloc((size_t)BATCH * 64 * 2);
  unsigned short* h1 = (unsigned short*)alloc((size_t)BATCH * 1024 * 2);
  unsigned short* h2 = (unsigned short*)alloc((size_t)BATCH * 1024 * 2);
  float* ksum = (float*)alloc((size_t)BATCH * 64 * 4);
  const int Kdim[5] = {64, 1024, 1024, 1024, 1024};
  const int Ndim[5] = {1024, 1024, 1024, 1024, 64};
  unsigned short* Wh[5];
  for (int i = 0; i < 5; ++i)
    Wh[i] = (unsigned short*)alloc((size_t)Ndim[i] * Kdim[i] * 2);

  for (int i = 0; i < 5; ++i) {
    const int total = Ndim[i] * Kdim[i];
    conv_w<<<(total + 255) / 256, 256, 0, stream>>>(W[i], Wh[i], Ndim[i], Kdim[i]);
  }
  init_y<<<BATCH * 64 / 256, 256, 0, stream>>>(x, aug, y, yh);

  const float dt = 0.125f;
  float* outp = (float*)d_out;

  auto eval = [&](float t, int mode, float* op) {
    // layer 0: [B,64] x [64,1024]^T -> h1
    gemm_h<128, 128, 4, 4, 64, 1024, true>
        <<<dim3(BATCH / 128, 1024 / 128), 256, 0, stream>>>(
            yh, Wh[0], W[0], b[0], t, h1);
    unsigned short* src = h1;
    unsigned short* dst = h2;
    for (int L = 1; L <= 3; ++L) {
      gemm_h<128, 128, 4, 4, 1024, 1024, true>
          <<<dim3(BATCH / 128, 1024 / 128), 256, 0, stream>>>(
              src, Wh[L], W[L], b[L], t, dst);
      unsigned short* tmp = src; src = dst; dst = tmp;
    }
    gemm_l4<<<dim3(BATCH / 32, 1), 256, 0, stream>>>(
        src, Wh[4], W[4], b[4], t, y, ksum, yh, op, mode, dt);
  };

  for (int s = 0; s < 8; ++s) {
    const float t0 = s * dt;
    eval(t0, 0, nullptr);
    eval(t0 + 0.5f * dt, 1, nullptr);
    eval(t0 + 0.5f * dt, 2, nullptr);
    eval(t0 + dt, 3, (s == 7) ? outp : nullptr);
  }
}

// Round 8
// 4893.242 us; speedup vs baseline: 1.0051x; 1.0051x over previous
//
#include <hip/hip_runtime.h>
#include <cstdint>
#include <cstddef>

#define BATCH 16384

typedef float f32x4 __attribute__((ext_vector_type(4)));
typedef float f32x16 __attribute__((ext_vector_type(16)));
typedef _Float16 f16x8 __attribute__((ext_vector_type(8)));

__device__ __forceinline__ unsigned short f2h_bits(float f) {
  _Float16 h = (_Float16)f;
  return __builtin_bit_cast(unsigned short, h);
}

__device__ __forceinline__ void async_cp16(const void* g, void* l) {
  __builtin_amdgcn_global_load_lds(
      (const __attribute__((address_space(1))) unsigned int*)g,
      (__attribute__((address_space(3))) unsigned int*)l, 16, 0, 0);
}

// Barrier WITHOUT the full vmcnt(0) drain __syncthreads would force.
#define PIPE_BAR_6() asm volatile("s_waitcnt vmcnt(6)\n\ts_barrier" ::: "memory")
#define PIPE_BAR_0() asm volatile("s_waitcnt vmcnt(0)\n\ts_barrier" ::: "memory")

// ---------------------------------------------------------------------------
// Hidden-layer GEMM = R6 champion structure + 32x32x16 MFMA.
// C = relu(A[M,K] * Bw[N,K]^T + (bias + t*W[:,K])).
// Block 256x128, 4 waves 2x2, wave tile 128x64 = RT(4) x CT(2) tiles of
// 32x32, BK=32, 3-stage LDS pipeline with s_waitcnt vmcnt(6)+s_barrier
// (stage k+1's 6 loads stay in flight through compute(k)).
// 32x32x16 vs 16x16x32: same fragment bytes per MFMA but 2x the MACs ->
// halves ds_read traffic and instruction count per FLOP.
// A/B frag: row=lane&31, k=(lane>>5)*8+j (16B contiguous -> ds_read_b128).
// XOR swizzle cp = c ^ ((row>>1)&3): 8 consecutive rows cover all 32 banks.
// ---------------------------------------------------------------------------
template <int BM, int BN, int RT, int CT, int K, int N, bool RELU>
__launch_bounds__(256, 2)
__global__ void gemm_h(const unsigned short* __restrict__ A,
                       const unsigned short* __restrict__ Bw,
                       const float* __restrict__ Wfull,
                       const float* __restrict__ bias,
                       float tval,
                       unsigned short* __restrict__ Ch) {
  constexpr int BK = 32;
  constexpr int NI = K / BK;
  static_assert(NI >= 2, "pipeline needs >=2 stages");
  static_assert((BM * 4 + BN * 4) / 256 == 6, "vmcnt(6) assumes 6 loads/stage");
  static_assert(BM == 2 * RT * 32 && BN == 2 * CT * 32, "2x2 waves of 32-tiles");
  __shared__ __align__(16) unsigned short smA[3][BM * BK];
  __shared__ __align__(16) unsigned short smB[3][BN * BK];
  __shared__ float biasLds[BN];

  const int tid = threadIdx.x;
  const int wave = tid >> 6;
  const int lane = tid & 63;
  const int l32 = lane & 31;
  const int khalf = lane >> 5;  // which 8-k group this lane holds

  const int rowA0 = blockIdx.x * BM;
  const int rowB0 = blockIdx.y * BN;
  const int waveM = wave >> 1;  // 2 wave-rows
  const int waveN = wave & 1;   // 2 wave-cols

  // effective bias = b[col] + t * W[col][K] (time-column fold); its vmcnt
  // drain happens once, before the pipeline starts.
  if (tid < BN) {
    const int col = rowB0 + tid;
    biasLds[tid] = bias[col] + tval * Wfull[(size_t)col * (K + 1) + K];
  }

  auto stage = [&](int k0, int buf) {
#pragma unroll
    for (int i = 0; i < BM * 4 / 256; ++i) {
      const int s = i * 256 + tid;                // LDS 16B-chunk position
      const int row = s >> 2;
      const int c = (s & 3) ^ ((row >> 1) & 3);   // global chunk (swizzled)
      const unsigned short* g = A + (size_t)(rowA0 + row) * K + (k0 + c * 8);
      char* l = ((char*)smA[buf]) + (size_t)(i * 256 + (wave << 6)) * 16;
      async_cp16(g, l);
    }
#pragma unroll
    for (int i = 0; i < BN * 4 / 256; ++i) {
      const int s = i * 256 + tid;
      const int row = s >> 2;
      const int c = (s & 3) ^ ((row >> 1) & 3);
      const unsigned short* g = Bw + (size_t)(rowB0 + row) * K + (k0 + c * 8);
      char* l = ((char*)smB[buf]) + (size_t)(i * 256 + (wave << 6)) * 16;
      async_cp16(g, l);
    }
  };

  f32x16 acc[RT][CT];
#pragma unroll
  for (int i = 0; i < RT; ++i)
#pragma unroll
    for (int j = 0; j < CT; ++j)
#pragma unroll
      for (int r = 0; r < 16; ++r) acc[i][j][r] = 0.f;

  auto compute = [&](int buf) {
    const unsigned short* sA = smA[buf];
    const unsigned short* sB = smB[buf];
#pragma unroll
    for (int h = 0; h < 2; ++h) {           // two k-halves of 16 per BK=32
      const int kc = h * 2 + khalf;         // global 16B-chunk index
      f16x8 af[RT], bfr[CT];
#pragma unroll
      for (int nt = 0; nt < CT; ++nt) {
        const int row = waveN * (CT * 32) + nt * 32 + l32;
        const int cp = kc ^ ((row >> 1) & 3);
        bfr[nt] = *(const f16x8*)(sB + row * BK + cp * 8);
      }
#pragma unroll
      for (int mt = 0; mt < RT; ++mt) {
        const int row = waveM * (RT * 32) + mt * 32 + l32;
        const int cp = kc ^ ((row >> 1) & 3);
        af[mt] = *(const f16x8*)(sA + row * BK + cp * 8);
      }
#pragma unroll
      for (int mt = 0; mt < RT; ++mt)
#pragma unroll
        for (int nt = 0; nt < CT; ++nt)
          acc[mt][nt] = __builtin_amdgcn_mfma_f32_32x32x16_f16(
              af[mt], bfr[nt], acc[mt][nt], 0, 0, 0);
    }
  };

  stage(0, 0);
  stage(BK, 1);

#pragma unroll
  for (int kk = 0; kk < NI - 1; ++kk) {
    PIPE_BAR_6();  // stage kk complete; stage kk+1 still in flight
    if (kk + 2 < NI) stage((kk + 2) * BK, (kk + 2) % 3);
    compute(kk % 3);
  }
  PIPE_BAR_0();  // tail: drain the final stage
  compute((NI - 1) % 3);

  // epilogue: 32x32 C/D layout col=lane&31, row=(reg&3)+8*(reg>>2)+4*(lane>>5)
#pragma unroll
  for (int mt = 0; mt < RT; ++mt) {
    const int rowBase = rowA0 + waveM * (RT * 32) + mt * 32 + khalf * 4;
#pragma unroll
    for (int nt = 0; nt < CT; ++nt) {
      const int lcol = waveN * (CT * 32) + nt * 32 + l32;
      const int gcol = rowB0 + lcol;
      const float bi = biasLds[lcol];
#pragma unroll
      for (int r = 0; r < 16; ++r) {
        float v = acc[mt][nt][r] + bi;
        if (RELU) v = fmaxf(v, 0.0f);
        const int grow = rowBase + (r & 3) + 8 * (r >> 2);
        Ch[(size_t)grow * N + gcol] = f2h_bits(v);
      }
    }
  }
}

// ---------------------------------------------------------------------------
// Last layer fused with RK4 combine (BM=32, BN=64 full width), dbuf BK=32.
// ---------------------------------------------------------------------------
__launch_bounds__(256, 4)
__global__ void gemm_l4(const unsigned short* __restrict__ A,
                        const unsigned short* __restrict__ Bw,
                        const float* __restrict__ Wfull,
                        const float* __restrict__ bias,
                        float tval,
                        float* __restrict__ y, float* __restrict__ ksum,
                        unsigned short* __restrict__ yh,
                        float* __restrict__ outp, int mode, float dt) {
  constexpr int K = 1024, BK = 32, BM = 32, BN = 64, NI = K / BK;
  __shared__ __align__(16) unsigned short smA[2][BM * BK];
  __shared__ __align__(16) unsigned short smB[2][BN * BK];
  __shared__ float biasLds[BN];

  const int tid = threadIdx.x;
  const int wave = tid >> 6;
  const int lane = tid & 63;
  const int quad = lane >> 4;
  const int r16 = lane & 15;

  const int rowA0 = blockIdx.x * BM;
  const int waveM = wave >> 1;
  const int waveN = wave & 1;

  if (tid < BN) {
    biasLds[tid] = bias[tid] + tval * Wfull[(size_t)tid * (K + 1) + K];
  }

  auto stage = [&](int k0, int buf) {
    if (tid < BM * 4) {  // A: 128 chunks
      const int s = tid;
      const int row = s >> 2;
      const int c = (s & 3) ^ ((row >> 1) & 3);
      const unsigned short* g = A + (size_t)(rowA0 + row) * K + (k0 + c * 8);
      char* l = ((char*)smA[buf]) + (size_t)(wave << 6) * 16;
      async_cp16(g, l);
    }
    {  // B: 256 chunks
      const int s = tid;
      const int row = s >> 2;
      const int c = (s & 3) ^ ((row >> 1) & 3);
      const unsigned short* g = Bw + (size_t)row * K + (k0 + c * 8);
      char* l = ((char*)smB[buf]) + (size_t)(wave << 6) * 16;
      async_cp16(g, l);
    }
  };

  f32x4 acc[2];
  const f32x4 zero = {0.f, 0.f, 0.f, 0.f};
  acc[0] = zero; acc[1] = zero;

  stage(0, 0);

#pragma unroll 2
  for (int kk = 0; kk < NI; ++kk) {
    __syncthreads();
    if (kk + 1 < NI) stage((kk + 1) * BK, (kk + 1) & 1);

    const unsigned short* sA = smA[kk & 1];
    const unsigned short* sB = smB[kk & 1];
    f16x8 af, bfr[2];
    {
      const int row = waveM * 16 + r16;
      const int cp = quad ^ ((row >> 1) & 3);
      af = *(const f16x8*)(sA + row * BK + cp * 8);
    }
#pragma unroll
    for (int nt = 0; nt < 2; ++nt) {
      const int row = (waveN * 2 + nt) * 16 + r16;
      const int cp = quad ^ ((row >> 1) & 3);
      bfr[nt] = *(const f16x8*)(sB + row * BK + cp * 8);
    }
#pragma unroll
    for (int nt = 0; nt < 2; ++nt)
      acc[nt] = __builtin_amdgcn_mfma_f32_16x16x32_f16(af, bfr[nt], acc[nt], 0, 0, 0);
  }

  // epilogue + fused RK4 combine
  const int grow0 = rowA0 + waveM * 16 + quad * 4;
#pragma unroll
  for (int nt = 0; nt < 2; ++nt) {
    const int col = waveN * 32 + nt * 16 + r16;
    const float bi = biasLds[col];
#pragma unroll
    for (int r = 0; r < 4; ++r) {
      const float k = acc[nt][r] + bi;
      const int row = grow0 + r;
      const int idx = row * 64 + col;
      if (mode == 0) {
        ksum[idx] = k;
        yh[idx] = f2h_bits(y[idx] + 0.5f * dt * k);
      } else if (mode == 1) {
        ksum[idx] += 2.f * k;
        yh[idx] = f2h_bits(y[idx] + 0.5f * dt * k);
      } else if (mode == 2) {
        ksum[idx] += 2.f * k;
        yh[idx] = f2h_bits(y[idx] + dt * k);
      } else {
        const float yn = y[idx] + (dt / 6.f) * (ksum[idx] + k);
        y[idx] = yn;
        yh[idx] = f2h_bits(yn);
        if (outp && col < 32) outp[row * 32 + col] = yn;
      }
    }
  }
}

// fp32 W (N x (K+1), time col dropped) -> fp16 Wh (N x K), row-major
__global__ void conv_w(const float* __restrict__ W, unsigned short* __restrict__ Wh,
                       int N, int K) {
  const int idx = blockIdx.x * 256 + threadIdx.x;
  if (idx < N * K) {
    const int n = idx / K;
    const int k = idx - n * K;
    Wh[idx] = f2h_bits(W[(size_t)n * (K + 1) + k]);
  }
}

// y0 = concat(x, aug); row-major fp32 + fp16 copy
__global__ void init_y(const float* __restrict__ x, const float* __restrict__ aug,
                       float* __restrict__ y, unsigned short* __restrict__ yh) {
  const int idx = blockIdx.x * 256 + threadIdx.x;  // BATCH*64
  const int i = idx >> 6;
  const int j = idx & 63;
  const float v = (j < 32) ? x[i * 32 + j] : aug[i * 32 + (j - 32)];
  y[idx] = v;
  yh[idx] = f2h_bits(v);
}

extern "C" void kernel_launch(void* const* d_in, const int* in_sizes, int n_in,
                              void* d_out, int out_size, void* d_ws, size_t ws_size,
                              hipStream_t stream) {
  const float* x = (const float*)d_in[0];
  const float* aug = (const float*)d_in[1];
  const float* W[5];
  const float* b[5];
  for (int i = 0; i < 5; ++i) {
    W[i] = (const float*)d_in[2 + 2 * i];
    b[i] = (const float*)d_in[3 + 2 * i];
  }

  char* ws = (char*)d_ws;
  auto alloc = [&](size_t bytes) -> char* {
    char* p = ws;
    ws += (bytes + 255) & ~(size_t)255;
    return p;
  };
  float* y = (float*)alloc((size_t)BATCH * 64 * 4);
  unsigned short* yh = (unsigned short*)alloc((size_t)BATCH * 64 * 2);
  unsigned short* h1 = (unsigned short*)alloc((size_t)BATCH * 1024 * 2);
  unsigned short* h2 = (unsigned short*)alloc((size_t)BATCH * 1024 * 2);
  float* ksum = (float*)alloc((size_t)BATCH * 64 * 4);
  const int Kdim[5] = {64, 1024, 1024, 1024, 1024};
  const int Ndim[5] = {1024, 1024, 1024, 1024, 64};
  unsigned short* Wh[5];
  for (int i = 0; i < 5; ++i)
    Wh[i] = (unsigned short*)alloc((size_t)Ndim[i] * Kdim[i] * 2);

  for (int i = 0; i < 5; ++i) {
    const int total = Ndim[i] * Kdim[i];
    conv_w<<<(total + 255) / 256, 256, 0, stream>>>(W[i], Wh[i], Ndim[i], Kdim[i]);
  }
  init_y<<<BATCH * 64 / 256, 256, 0, stream>>>(x, aug, y, yh);

  const float dt = 0.125f;
  float* outp = (float*)d_out;

  auto eval = [&](float t, int mode, float* op) {
    // layer 0: [B,64] x [64,1024]^T -> h1
    gemm_h<256, 128, 4, 2, 64, 1024, true>
        <<<dim3(BATCH / 256, 1024 / 128), 256, 0, stream>>>(
            yh, Wh[0], W[0], b[0], t, h1);
    unsigned short* src = h1;
    unsigned short* dst = h2;
    for (int L = 1; L <= 3; ++L) {
      gemm_h<256, 128, 4, 2, 1024, 1024, true>
          <<<dim3(BATCH / 256, 1024 / 128), 256, 0, stream>>>(
              src, Wh[L], W[L], b[L], t, dst);
      unsigned short* tmp = src; src = dst; dst = tmp;
    }
    gemm_l4<<<dim3(BATCH / 32, 1), 256, 0, stream>>>(
        src, Wh[4], W[4], b[4], t, y, ksum, yh, op, mode, dt);
  };

  for (int s = 0; s < 8; ++s) {
    const float t0 = s * dt;
    eval(t0, 0, nullptr);
    eval(t0 + 0.5f * dt, 1, nullptr);
    eval(t0 + 0.5f * dt, 2, nullptr);
    eval(t0 + dt, 3, (s == 7) ? outp : nullptr);
  }
}

// Round 9
// 4427.324 us; speedup vs baseline: 1.1108x; 1.1052x over previous
//
#include <hip/hip_runtime.h>
#include <cstdint>
#include <cstddef>

#define BATCH 16384

typedef float f32x4 __attribute__((ext_vector_type(4)));
typedef _Float16 f16x8 __attribute__((ext_vector_type(8)));

__device__ __forceinline__ unsigned short f2h_bits(float f) {
  _Float16 h = (_Float16)f;
  return __builtin_bit_cast(unsigned short, h);
}

__device__ __forceinline__ void async_cp16(const void* g, void* l) {
  __builtin_amdgcn_global_load_lds(
      (const __attribute__((address_space(1))) unsigned int*)g,
      (__attribute__((address_space(3))) unsigned int*)l, 16, 0, 0);
}

// Barrier WITHOUT the full vmcnt(0) drain __syncthreads would force.
#define PIPE_BAR_3() asm volatile("s_waitcnt vmcnt(3)\n\ts_barrier" ::: "memory")
#define PIPE_BAR_0() asm volatile("s_waitcnt vmcnt(0)\n\ts_barrier" ::: "memory")

// ---------------------------------------------------------------------------
// Hidden-layer GEMM: R6 champion tile + DOUBLED occupancy via 512-thr blocks.
// C = relu(A[M,K] * Bw[N,K]^T + (bias + t*W[:,K])).
// Block tile 256x128, 8 waves in 4x2, wave tile 64x64 (RT=CT=4, acc=64 VGPR),
// BK=32, 3-stage LDS pipeline: iter k waits s_waitcnt vmcnt(3) (stage k's 3
// loads done, stage k+1's 3 STAY IN FLIGHT through compute(k)), s_barrier,
// issues stage k+2. LDS 72.5 KB -> 2 blocks/CU x 8 waves = 4 waves/SIMD
// (R6 had 2/SIMD; occupancy was the binding constraint: all pipes <30%).
// VGPR budget for 4 waves/SIMD is 128; acc 64 + frags 32 fits.
// XOR swizzle cp = c ^ ((row>>1)&3): frag ds_read_b128 2-way max (free).
// ---------------------------------------------------------------------------
template <int BM, int BN, int RT, int CT, int K, int N, bool RELU>
__launch_bounds__(512, 4)
__global__ void gemm_h(const unsigned short* __restrict__ A,
                       const unsigned short* __restrict__ Bw,
                       const float* __restrict__ Wfull,
                       const float* __restrict__ bias,
                       float tval,
                       unsigned short* __restrict__ Ch) {
  constexpr int BK = 32;
  constexpr int NI = K / BK;
  static_assert(NI >= 2, "pipeline needs >=2 stages");
  static_assert((BM * 4 + BN * 4) / 512 == 3, "vmcnt(3) assumes 3 loads/stage");
  static_assert(BM == 4 * RT * 16 && BN == 2 * CT * 16, "4x2 waves");
  __shared__ __align__(16) unsigned short smA[3][BM * BK];
  __shared__ __align__(16) unsigned short smB[3][BN * BK];
  __shared__ float biasLds[BN];

  const int tid = threadIdx.x;
  const int wave = tid >> 6;
  const int lane = tid & 63;
  const int quad = lane >> 4;
  const int r16 = lane & 15;

  const int rowA0 = blockIdx.x * BM;
  const int rowB0 = blockIdx.y * BN;
  const int waveM = wave >> 1;  // 4 wave-rows
  const int waveN = wave & 1;   // 2 wave-cols

  // effective bias = b[col] + t * W[col][K] (time-column fold); its vmcnt
  // drain happens once, before the pipeline starts.
  if (tid < BN) {
    const int col = rowB0 + tid;
    biasLds[tid] = bias[col] + tval * Wfull[(size_t)col * (K + 1) + K];
  }

  auto stage = [&](int k0, int buf) {
#pragma unroll
    for (int i = 0; i < BM * 4 / 512; ++i) {  // A: 1024 chunks, 2/thread
      const int s = i * 512 + tid;                // LDS 16B-chunk position
      const int row = s >> 2;
      const int c = (s & 3) ^ ((row >> 1) & 3);   // global chunk (swizzled)
      const unsigned short* g = A + (size_t)(rowA0 + row) * K + (k0 + c * 8);
      char* l = ((char*)smA[buf]) + (size_t)(i * 512 + (wave << 6)) * 16;
      async_cp16(g, l);
    }
    {  // B: 512 chunks, 1/thread
      const int s = tid;
      const int row = s >> 2;
      const int c = (s & 3) ^ ((row >> 1) & 3);
      const unsigned short* g = Bw + (size_t)(rowB0 + row) * K + (k0 + c * 8);
      char* l = ((char*)smB[buf]) + (size_t)((wave << 6)) * 16;
      async_cp16(g, l);
    }
  };

  f32x4 acc[RT][CT];
  const f32x4 zero = {0.f, 0.f, 0.f, 0.f};
#pragma unroll
  for (int i = 0; i < RT; ++i)
#pragma unroll
    for (int j = 0; j < CT; ++j) acc[i][j] = zero;

  auto compute = [&](int buf) {
    const unsigned short* sA = smA[buf];
    const unsigned short* sB = smB[buf];
    f16x8 af[RT], bfr[CT];
#pragma unroll
    for (int nt = 0; nt < CT; ++nt) {
      const int row = waveN * (CT * 16) + nt * 16 + r16;
      const int cp = quad ^ ((row >> 1) & 3);
      bfr[nt] = *(const f16x8*)(sB + row * BK + cp * 8);
    }
#pragma unroll
    for (int mt = 0; mt < RT; ++mt) {
      const int row = waveM * (RT * 16) + mt * 16 + r16;
      const int cp = quad ^ ((row >> 1) & 3);
      af[mt] = *(const f16x8*)(sA + row * BK + cp * 8);
    }
#pragma unroll
    for (int mt = 0; mt < RT; ++mt)
#pragma unroll
      for (int nt = 0; nt < CT; ++nt)
        acc[mt][nt] =
            __builtin_amdgcn_mfma_f32_16x16x32_f16(af[mt], bfr[nt], acc[mt][nt], 0, 0, 0);
  };

  stage(0, 0);
  stage(BK, 1);

#pragma unroll
  for (int kk = 0; kk < NI - 1; ++kk) {
    PIPE_BAR_3();  // stage kk complete; stage kk+1 still in flight
    if (kk + 2 < NI) stage((kk + 2) * BK, (kk + 2) % 3);
    compute(kk % 3);
  }
  PIPE_BAR_0();  // tail: drain the final stage
  compute((NI - 1) % 3);

  // epilogue: C/D layout col=lane&15, row=(lane>>4)*4+r
#pragma unroll
  for (int mt = 0; mt < RT; ++mt) {
    const int grow0 = rowA0 + waveM * (RT * 16) + mt * 16 + quad * 4;
#pragma unroll
    for (int nt = 0; nt < CT; ++nt) {
      const int lcol = waveN * (CT * 16) + nt * 16 + r16;
      const int gcol = rowB0 + lcol;
      const float bi = biasLds[lcol];
#pragma unroll
      for (int r = 0; r < 4; ++r) {
        float v = acc[mt][nt][r] + bi;
        if (RELU) v = fmaxf(v, 0.0f);
        Ch[(size_t)(grow0 + r) * N + gcol] = f2h_bits(v);
      }
    }
  }
}

// ---------------------------------------------------------------------------
// Last layer fused with RK4 combine (BM=32, BN=64 full width), dbuf BK=32.
// ---------------------------------------------------------------------------
__launch_bounds__(256, 4)
__global__ void gemm_l4(const unsigned short* __restrict__ A,
                        const unsigned short* __restrict__ Bw,
                        const float* __restrict__ Wfull,
                        const float* __restrict__ bias,
                        float tval,
                        float* __restrict__ y, float* __restrict__ ksum,
                        unsigned short* __restrict__ yh,
                        float* __restrict__ outp, int mode, float dt) {
  constexpr int K = 1024, BK = 32, BM = 32, BN = 64, NI = K / BK;
  __shared__ __align__(16) unsigned short smA[2][BM * BK];
  __shared__ __align__(16) unsigned short smB[2][BN * BK];
  __shared__ float biasLds[BN];

  const int tid = threadIdx.x;
  const int wave = tid >> 6;
  const int lane = tid & 63;
  const int quad = lane >> 4;
  const int r16 = lane & 15;

  const int rowA0 = blockIdx.x * BM;
  const int waveM = wave >> 1;
  const int waveN = wave & 1;

  if (tid < BN) {
    biasLds[tid] = bias[tid] + tval * Wfull[(size_t)tid * (K + 1) + K];
  }

  auto stage = [&](int k0, int buf) {
    if (tid < BM * 4) {  // A: 128 chunks
      const int s = tid;
      const int row = s >> 2;
      const int c = (s & 3) ^ ((row >> 1) & 3);
      const unsigned short* g = A + (size_t)(rowA0 + row) * K + (k0 + c * 8);
      char* l = ((char*)smA[buf]) + (size_t)(wave << 6) * 16;
      async_cp16(g, l);
    }
    {  // B: 256 chunks
      const int s = tid;
      const int row = s >> 2;
      const int c = (s & 3) ^ ((row >> 1) & 3);
      const unsigned short* g = Bw + (size_t)row * K + (k0 + c * 8);
      char* l = ((char*)smB[buf]) + (size_t)(wave << 6) * 16;
      async_cp16(g, l);
    }
  };

  f32x4 acc[2];
  const f32x4 zero = {0.f, 0.f, 0.f, 0.f};
  acc[0] = zero; acc[1] = zero;

  stage(0, 0);

#pragma unroll 2
  for (int kk = 0; kk < NI; ++kk) {
    __syncthreads();
    if (kk + 1 < NI) stage((kk + 1) * BK, (kk + 1) & 1);

    const unsigned short* sA = smA[kk & 1];
    const unsigned short* sB = smB[kk & 1];
    f16x8 af, bfr[2];
    {
      const int row = waveM * 16 + r16;
      const int cp = quad ^ ((row >> 1) & 3);
      af = *(const f16x8*)(sA + row * BK + cp * 8);
    }
#pragma unroll
    for (int nt = 0; nt < 2; ++nt) {
      const int row = (waveN * 2 + nt) * 16 + r16;
      const int cp = quad ^ ((row >> 1) & 3);
      bfr[nt] = *(const f16x8*)(sB + row * BK + cp * 8);
    }
#pragma unroll
    for (int nt = 0; nt < 2; ++nt)
      acc[nt] = __builtin_amdgcn_mfma_f32_16x16x32_f16(af, bfr[nt], acc[nt], 0, 0, 0);
  }

  // epilogue + fused RK4 combine
  const int grow0 = rowA0 + waveM * 16 + quad * 4;
#pragma unroll
  for (int nt = 0; nt < 2; ++nt) {
    const int col = waveN * 32 + nt * 16 + r16;
    const float bi = biasLds[col];
#pragma unroll
    for (int r = 0; r < 4; ++r) {
      const float k = acc[nt][r] + bi;
      const int row = grow0 + r;
      const int idx = row * 64 + col;
      if (mode == 0) {
        ksum[idx] = k;
        yh[idx] = f2h_bits(y[idx] + 0.5f * dt * k);
      } else if (mode == 1) {
        ksum[idx] += 2.f * k;
        yh[idx] = f2h_bits(y[idx] + 0.5f * dt * k);
      } else if (mode == 2) {
        ksum[idx] += 2.f * k;
        yh[idx] = f2h_bits(y[idx] + dt * k);
      } else {
        const float yn = y[idx] + (dt / 6.f) * (ksum[idx] + k);
        y[idx] = yn;
        yh[idx] = f2h_bits(yn);
        if (outp && col < 32) outp[row * 32 + col] = yn;
      }
    }
  }
}

// fp32 W (N x (K+1), time col dropped) -> fp16 Wh (N x K), row-major
__global__ void conv_w(const float* __restrict__ W, unsigned short* __restrict__ Wh,
                       int N, int K) {
  const int idx = blockIdx.x * 256 + threadIdx.x;
  if (idx < N * K) {
    const int n = idx / K;
    const int k = idx - n * K;
    Wh[idx] = f2h_bits(W[(size_t)n * (K + 1) + k]);
  }
}

// y0 = concat(x, aug); row-major fp32 + fp16 copy
__global__ void init_y(const float* __restrict__ x, const float* __restrict__ aug,
                       float* __restrict__ y, unsigned short* __restrict__ yh) {
  const int idx = blockIdx.x * 256 + threadIdx.x;  // BATCH*64
  const int i = idx >> 6;
  const int j = idx & 63;
  const float v = (j < 32) ? x[i * 32 + j] : aug[i * 32 + (j - 32)];
  y[idx] = v;
  yh[idx] = f2h_bits(v);
}

extern "C" void kernel_launch(void* const* d_in, const int* in_sizes, int n_in,
                              void* d_out, int out_size, void* d_ws, size_t ws_size,
                              hipStream_t stream) {
  const float* x = (const float*)d_in[0];
  const float* aug = (const float*)d_in[1];
  const float* W[5];
  const float* b[5];
  for (int i = 0; i < 5; ++i) {
    W[i] = (const float*)d_in[2 + 2 * i];
    b[i] = (const float*)d_in[3 + 2 * i];
  }

  char* ws = (char*)d_ws;
  auto alloc = [&](size_t bytes) -> char* {
    char* p = ws;
    ws += (bytes + 255) & ~(size_t)255;
    return p;
  };
  float* y = (float*)alloc((size_t)BATCH * 64 * 4);
  unsigned short* yh = (unsigned short*)alloc((size_t)BATCH * 64 * 2);
  unsigned short* h1 = (unsigned short*)alloc((size_t)BATCH * 1024 * 2);
  unsigned short* h2 = (unsigned short*)alloc((size_t)BATCH * 1024 * 2);
  float* ksum = (float*)alloc((size_t)BATCH * 64 * 4);
  const int Kdim[5] = {64, 1024, 1024, 1024, 1024};
  const int Ndim[5] = {1024, 1024, 1024, 1024, 64};
  unsigned short* Wh[5];
  for (int i = 0; i < 5; ++i)
    Wh[i] = (unsigned short*)alloc((size_t)Ndim[i] * Kdim[i] * 2);

  for (int i = 0; i < 5; ++i) {
    const int total = Ndim[i] * Kdim[i];
    conv_w<<<(total + 255) / 256, 256, 0, stream>>>(W[i], Wh[i], Ndim[i], Kdim[i]);
  }
  init_y<<<BATCH * 64 / 256, 256, 0, stream>>>(x, aug, y, yh);

  const float dt = 0.125f;
  float* outp = (float*)d_out;

  auto eval = [&](float t, int mode, float* op) {
    // layer 0: [B,64] x [64,1024]^T -> h1
    gemm_h<256, 128, 4, 4, 64, 1024, true>
        <<<dim3(BATCH / 256, 1024 / 128), 512, 0, stream>>>(
            yh, Wh[0], W[0], b[0], t, h1);
    unsigned short* src = h1;
    unsigned short* dst = h2;
    for (int L = 1; L <= 3; ++L) {
      gemm_h<256, 128, 4, 4, 1024, 1024, true>
          <<<dim3(BATCH / 256, 1024 / 128), 512, 0, stream>>>(
              src, Wh[L], W[L], b[L], t, dst);
      unsigned short* tmp = src; src = dst; dst = tmp;
    }
    gemm_l4<<<dim3(BATCH / 32, 1), 256, 0, stream>>>(
        src, Wh[4], W[4], b[4], t, y, ksum, yh, op, mode, dt);
  };

  for (int s = 0; s < 8; ++s) {
    const float t0 = s * dt;
    eval(t0, 0, nullptr);
    eval(t0 + 0.5f * dt, 1, nullptr);
    eval(t0 + 0.5f * dt, 2, nullptr);
    eval(t0 + dt, 3, (s == 7) ? outp : nullptr);
  }
}